// Round 2
// baseline (906.112 us; speedup 1.0000x reference)
//
#include <hip/hip_runtime.h>
#include <hip/hip_fp16.h>
#include <math.h>

#define N_LEVELS 16
#define LOG2_T 19
#define TABLE_SIZE (1 << LOG2_T)

typedef float f2_t __attribute__((ext_vector_type(2)));

struct Params {
    float res[N_LEVELS];
    int   fb[9];    // filler-pool boundaries per slot (global filler-chunk index)
    int   M;        // chunks per level (256 points each)
    int   n_pts;
};

// ---- pass 1: f32 -> f16 table compression into workspace (~20 us, every launch
// because the harness may re-poison the workspace). Values in [-1e-4,1e-4];
// fp16 RTN abs error <= ~2.4e-8 (measured: absmax identical to f32 baseline).
__global__ __launch_bounds__(256) void convert_tables_f16(
    const f2_t* __restrict__ emb, unsigned* __restrict__ tab, int n_entries)
{
    int i = blockIdx.x * 256 + threadIdx.x;
    if (i >= n_entries) return;
    f2_t e = __builtin_nontemporal_load(&emb[i]);
    union { __half2 h2; unsigned u; } cvt;
    cvt.h2 = __floats2half2_rn(e.x, e.y);
    __builtin_nontemporal_store(cvt.u, &tab[i]);
}

// ---- pass 2: cost-balanced level->XCD schedule.
// XCD = blockIdx % 8 (round-robin dispatch, verified by round-1 FETCH collapse).
// Slot s owns: primary fine level (8+s) in full, plus a weighted slice of the
// filler pool {L7,L6,...,L0}. Weighted load per slot = 1.42 units vs the
// round-1 critical slot's 2.0 -> fixes the 39% occupancy / idle-XCD imbalance.
// Hot tables stay in that XCD's L2 (<=4MB fp16 for most slots; overflow hits
// the 256MB L3 which holds all tables).
template <bool HALF>
__global__ __launch_bounds__(256) void ingp_hash_bal(
    const float* __restrict__ x,
    const void* __restrict__ tb,
    float* __restrict__ out,
    Params P)
{
    int b    = blockIdx.x;
    int slot = b & 7;           // -> XCD
    int pos  = b >> 3;

    int level, chunk;
    if (pos < P.M) {            // primary: full fine level 8+slot
        level = 8 + slot;
        chunk = pos;
    } else {                    // filler slice [fb[s], fb[s+1]) of pool L7..L0
        int g = P.fb[slot] + (pos - P.M);
        if (g >= P.fb[slot + 1]) return;   // padding block
        int i = g / P.M;        // pool index 0..7 -> level 7-i
        level = 7 - i;
        chunk = g - i * P.M;
    }

    int n = chunk * 256 + (int)threadIdx.x;
    if (n >= P.n_pts) return;

    // clip to [-1, 1]  (non-temporal: x stream must not evict tables from L2)
    float xx = fminf(fmaxf(__builtin_nontemporal_load(&x[n * 3 + 0]), -1.0f), 1.0f);
    float xy = fminf(fmaxf(__builtin_nontemporal_load(&x[n * 3 + 1]), -1.0f), 1.0f);
    float xz = fminf(fmaxf(__builtin_nontemporal_load(&x[n * 3 + 2]), -1.0f), 1.0f);

    float r = P.res[level];
    float grid = 2.0f / r;      // fp32 IEEE div == numpy

    // bottom-left voxel index: exact fp32 op sequence of the verified baseline.
    float tx = (xx + 1.0f) / grid;
    float ty = (xy + 1.0f) / grid;
    float tz = (xz + 1.0f) / grid;
    int blx = (int)floorf(tx);
    int bly = (int)floorf(ty);
    int blz = (int)floorf(tz);

    float wx = (xx - ((float)blx * grid + -1.0f)) / grid;
    float wy = (xy - ((float)bly * grid + -1.0f)) / grid;
    float wz = (xz - ((float)blz * grid + -1.0f)) / grid;

    const __half2* __restrict__ th = (const __half2*)tb + (size_t)level * TABLE_SIZE;
    const float2* __restrict__ tf  = (const float2*)tb + (size_t)level * TABLE_SIZE;

    float acc0 = 0.0f, acc1 = 0.0f;
#pragma unroll
    for (int k = 0; k < 8; ++k) {
        int bx = (k >> 2) & 1;
        int by = (k >> 1) & 1;
        int bz = k & 1;
        unsigned cx = (unsigned)(blx + bx);
        unsigned cy = (unsigned)(bly + by);
        unsigned cz = (unsigned)(blz + bz);
        unsigned h = cx ^ (cy * 2654435761u) ^ (cz * 805459861u);
        unsigned idx = h & (unsigned)(TABLE_SIZE - 1);
        float ex, ey;
        if (HALF) {
            __half2 e = th[idx];               // 4 B gather, L2-resident
            ex = __low2float(e);
            ey = __high2float(e);
        } else {
            float2 e = tf[idx];                // f32 fallback
            ex = e.x;
            ey = e.y;
        }
        float fx = bx ? wx : 1.0f - wx;
        float fy = by ? wy : 1.0f - wy;
        float fz = bz ? wz : 1.0f - wz;
        float wgt = (fx * fy) * fz;
        acc0 += wgt * ex;
        acc1 += wgt * ey;
    }

    f2_t o;
    o.x = acc0;
    o.y = acc1;
    __builtin_nontemporal_store(o, (f2_t*)(out + (size_t)n * (N_LEVELS * 2) + level * 2));
}

extern "C" void kernel_launch(void* const* d_in, const int* in_sizes, int n_in,
                              void* d_out, int out_size, void* d_ws, size_t ws_size,
                              hipStream_t stream) {
    const float* x   = (const float*)d_in[0];
    const float* emb = (const float*)d_in[1];
    float* out = (float*)d_out;
    int n_pts = in_sizes[0] / 3;

    Params P;
    // RESOLUTIONS: numpy float64 semantics on host (same libm as np).
    double b = exp((log(512.0) - log(16.0)) / 15.0);
    for (int i = 0; i < N_LEVELS; ++i) {
        P.res[i] = (float)floor(16.0 * pow(b, (double)i));
    }
    int M = (n_pts + 255) / 256;
    P.M = M;
    P.n_pts = n_pts;

    // Filler pool: index i -> level 7-i. Cost weights (issue-cost estimates:
    // full-hash levels ~1.0; coarse levels cheaper via L1 hits + coalescing,
    // hedged upward so a wrong guess can't recreate a 2.0-load slot).
    const double w[8] = {1.0, 0.9, 0.45, 0.30, 0.22, 0.18, 0.15, 0.15};
    double cum[9];
    cum[0] = 0.0;
    for (int i = 0; i < 8; ++i) cum[i + 1] = cum[i] + w[i];
    double share = cum[8] / 8.0;

    P.fb[0] = 0;
    P.fb[8] = 8 * M;
    for (int s = 1; s < 8; ++s) {
        double T = share * (double)s;
        int i = 0;
        while (i < 7 && cum[i + 1] <= T) ++i;
        int c = (int)((T - cum[i]) / w[i] * (double)M);
        if (c < 0) c = 0;
        if (c > M) c = M;
        P.fb[s] = i * M + c;
    }
    for (int s = 1; s < 9; ++s)               // monotonic guard
        if (P.fb[s] < P.fb[s - 1]) P.fb[s] = P.fb[s - 1];

    int maxK = 0;
    for (int s = 0; s < 8; ++s) {
        int K = M + (P.fb[s + 1] - P.fb[s]);
        if (K > maxK) maxK = K;
    }
    int blocks = 8 * maxK;

    size_t need = (size_t)N_LEVELS * TABLE_SIZE * sizeof(unsigned);  // 32 MB fp16
    if (ws_size >= need && d_ws != nullptr) {
        int n_entries = N_LEVELS * TABLE_SIZE;
        hipLaunchKernelGGL(convert_tables_f16,
                           dim3((n_entries + 255) / 256), dim3(256), 0, stream,
                           (const f2_t*)emb, (unsigned*)d_ws, n_entries);
        hipLaunchKernelGGL(HIP_KERNEL_NAME(ingp_hash_bal<true>),
                           dim3(blocks), dim3(256), 0, stream,
                           x, (const void*)d_ws, out, P);
    } else {
        hipLaunchKernelGGL(HIP_KERNEL_NAME(ingp_hash_bal<false>),
                           dim3(blocks), dim3(256), 0, stream,
                           x, (const void*)emb, out, P);
    }
}

// Round 3
// 673.976 us; speedup vs baseline: 1.3444x; 1.3444x over previous
//
#include <hip/hip_runtime.h>
#include <hip/hip_fp16.h>
#include <math.h>

#define N_LEVELS 16
#define LOG2_T 19
#define TABLE_SIZE (1 << LOG2_T)
#define IDX_MASK ((unsigned)(TABLE_SIZE - 1))

typedef float f2_t __attribute__((ext_vector_type(2)));
typedef float f4_t __attribute__((ext_vector_type(4)));

struct ResTable { float r[N_LEVELS]; };

// ---- pass 1: f32 -> f16 table compression into workspace (~25 us).
// Values in [-1e-4,1e-4]; fp16 abs error <= ~3e-8 (absmax measured identical
// to the f32 baseline in rounds 1-2).
__global__ __launch_bounds__(256) void convert_tables_f16(
    const f2_t* __restrict__ emb, unsigned* __restrict__ tab, int n_entries)
{
    int i = blockIdx.x * 256 + threadIdx.x;
    if (i >= n_entries) return;
    f2_t e = __builtin_nontemporal_load(&emb[i]);
    union { __half2 h2; unsigned u; } cvt;
    cvt.h2 = __floats2half2_rn(e.x, e.y);
    __builtin_nontemporal_store(cvt.u, &tab[i]);
}

// ---- pass 2: request-rate-optimized gather kernel.
// Regime (rounds 0-2): time tracks vector-memory REQUEST COUNT (~3.1 cyc per
// divergent lane-request), insensitive to residency and occupancy. So:
//  (a) hash-adjacency pair loads: x-prime == 1, so corners cx / cx+1 with cx
//      even hash to idx and idx^1 -> one aligned 8B load serves both corners
//      for even-blx lanes; odd lanes patch bx=1 with one exec-masked gather.
//      Gather requests per point-level: 8 -> 6 expected.
//  (b) one thread = one point x one LEVEL PAIR (2s, 2s+1): one float4 store
//      (16B-aligned in the (N,16,2) row) instead of two 8B stores; x loaded
//      once per pair. XCD slot s keeps tables {2s,2s+1} (<=4MB fp16) L2-resident.
template <bool HALF>
__global__ __launch_bounds__(256) void ingp_hash_pair(
    const float* __restrict__ x,
    const void* __restrict__ tb,
    float* __restrict__ out,
    int n_pts,
    ResTable res)
{
    int b     = blockIdx.x;
    int slot  = b & 7;            // -> XCD (round-robin dispatch)
    int chunk = b >> 3;
    int n = chunk * 256 + (int)threadIdx.x;
    if (n >= n_pts) return;

    // clip to [-1, 1]  (NT: keep the 16x-read x stream from evicting tables)
    float xx = fminf(fmaxf(__builtin_nontemporal_load(&x[n * 3 + 0]), -1.0f), 1.0f);
    float xy = fminf(fmaxf(__builtin_nontemporal_load(&x[n * 3 + 1]), -1.0f), 1.0f);
    float xz = fminf(fmaxf(__builtin_nontemporal_load(&x[n * 3 + 2]), -1.0f), 1.0f);

    f4_t o4;

#pragma unroll
    for (int hl = 0; hl < 2; ++hl) {
        int level = 2 * slot + hl;

        float r = res.r[level];
        float grid = 2.0f / r;    // fp32 IEEE div == numpy

        // exact fp32 op sequence of the verified baseline (add, div, floor)
        float tx = (xx + 1.0f) / grid;
        float ty = (xy + 1.0f) / grid;
        float tz = (xz + 1.0f) / grid;
        int blx = (int)floorf(tx);
        int bly = (int)floorf(ty);
        int blz = (int)floorf(tz);

        float wx = (xx - ((float)blx * grid + -1.0f)) / grid;
        float wy = (xy - ((float)bly * grid + -1.0f)) / grid;
        float wz = (xz - ((float)blz * grid + -1.0f)) / grid;

        unsigned ublx = (unsigned)blx;

        // hash contributions of the 4 (y,z) corner combos
        unsigned hy0 = (unsigned)bly * 2654435761u;
        unsigned hy1 = ((unsigned)bly + 1u) * 2654435761u;
        unsigned hz0 = (unsigned)blz * 805459861u;
        unsigned hz1 = ((unsigned)blz + 1u) * 805459861u;
        unsigned hyz[4] = { hy0 ^ hz0, hy0 ^ hz1, hy1 ^ hz0, hy1 ^ hz1 };

        float e0x[4], e0y[4], e1x[4], e1y[4];

        if (HALF) {
            const unsigned* __restrict__ tab =
                (const unsigned*)tb + (size_t)level * TABLE_SIZE;
            unsigned w0[4], w1[4];
#pragma unroll
            for (int yz = 0; yz < 4; ++yz) {
                unsigned i0 = (ublx ^ hyz[yz]) & IDX_MASK;   // bx=0 corner
                // aligned 8B pair {i0&~1, i0|1}; holds bx=0 always, and bx=1
                // too iff blx even (then i1 == i0^1)
                uint2 p = *(const uint2*)(tab + (i0 & ~1u));
                w0[yz] = (i0 & 1u) ? p.y : p.x;
                w1[yz] = (i0 & 1u) ? p.x : p.y;
            }
            if (ublx & 1u) {                 // odd lanes: real bx=1 corners
#pragma unroll
                for (int yz = 0; yz < 4; ++yz) {
                    unsigned i1 = ((ublx + 1u) ^ hyz[yz]) & IDX_MASK;
                    w1[yz] = tab[i1];
                }
            }
#pragma unroll
            for (int yz = 0; yz < 4; ++yz) {
                union { unsigned u; __half2 h; } a, bb;
                a.u = w0[yz]; bb.u = w1[yz];
                e0x[yz] = __low2float(a.h);  e0y[yz] = __high2float(a.h);
                e1x[yz] = __low2float(bb.h); e1y[yz] = __high2float(bb.h);
            }
        } else {
            const float* __restrict__ tab =
                (const float*)tb + (size_t)level * TABLE_SIZE * 2;
            f2_t w0[4], w1[4];
#pragma unroll
            for (int yz = 0; yz < 4; ++yz) {
                unsigned i0 = (ublx ^ hyz[yz]) & IDX_MASK;
                f4_t p = *(const f4_t*)(tab + (size_t)(i0 & ~1u) * 2); // 16B aligned
                bool hi = (i0 & 1u) != 0;
                w0[yz].x = hi ? p.z : p.x;  w0[yz].y = hi ? p.w : p.y;
                w1[yz].x = hi ? p.x : p.z;  w1[yz].y = hi ? p.y : p.w;
            }
            if (ublx & 1u) {
#pragma unroll
                for (int yz = 0; yz < 4; ++yz) {
                    unsigned i1 = ((ublx + 1u) ^ hyz[yz]) & IDX_MASK;
                    w1[yz] = *(const f2_t*)(tab + (size_t)i1 * 2);
                }
            }
#pragma unroll
            for (int yz = 0; yz < 4; ++yz) {
                e0x[yz] = w0[yz].x; e0y[yz] = w0[yz].y;
                e1x[yz] = w1[yz].x; e1y[yz] = w1[yz].y;
            }
        }

        // trilinear accumulate; yz bit order matches OFFSETS (by=yz>>1, bz=yz&1)
        float fy[2] = { 1.0f - wy, wy };
        float fz[2] = { 1.0f - wz, wz };
        float fx0 = 1.0f - wx, fx1 = wx;
        float acc0 = 0.0f, acc1 = 0.0f;
#pragma unroll
        for (int yz = 0; yz < 4; ++yz) {
            float wyz = fy[yz >> 1] * fz[yz & 1];
            float g0 = fx0 * wyz;
            float g1 = fx1 * wyz;
            acc0 += g0 * e0x[yz] + g1 * e1x[yz];
            acc1 += g0 * e0y[yz] + g1 * e1y[yz];
        }

        if (hl == 0) { o4.x = acc0; o4.y = acc1; }
        else         { o4.z = acc0; o4.w = acc1; }
    }

    // one 16B-aligned store covering levels {2s, 2s+1} of row n
    __builtin_nontemporal_store(o4, (f4_t*)(out + (size_t)n * (N_LEVELS * 2) + slot * 4));
}

extern "C" void kernel_launch(void* const* d_in, const int* in_sizes, int n_in,
                              void* d_out, int out_size, void* d_ws, size_t ws_size,
                              hipStream_t stream) {
    const float* x   = (const float*)d_in[0];
    const float* emb = (const float*)d_in[1];
    float* out = (float*)d_out;
    int n_pts = in_sizes[0] / 3;

    // RESOLUTIONS: numpy float64 semantics on host (same libm as np)
    ResTable res;
    double b = exp((log(512.0) - log(16.0)) / 15.0);
    for (int i = 0; i < N_LEVELS; ++i) {
        res.r[i] = (float)floor(16.0 * pow(b, (double)i));
    }

    int M = (n_pts + 255) / 256;
    int blocks = 8 * M;   // slot s (XCD s) handles level pair {2s, 2s+1}

    size_t need = (size_t)N_LEVELS * TABLE_SIZE * sizeof(unsigned);  // 32 MB fp16
    if (ws_size >= need && d_ws != nullptr) {
        int n_entries = N_LEVELS * TABLE_SIZE;
        hipLaunchKernelGGL(convert_tables_f16,
                           dim3((n_entries + 255) / 256), dim3(256), 0, stream,
                           (const f2_t*)emb, (unsigned*)d_ws, n_entries);
        hipLaunchKernelGGL(HIP_KERNEL_NAME(ingp_hash_pair<true>),
                           dim3(blocks), dim3(256), 0, stream,
                           x, (const void*)d_ws, out, n_pts, res);
    } else {
        hipLaunchKernelGGL(HIP_KERNEL_NAME(ingp_hash_pair<false>),
                           dim3(blocks), dim3(256), 0, stream,
                           x, (const void*)emb, out, n_pts, res);
    }
}

// Round 4
// 628.229 us; speedup vs baseline: 1.4423x; 1.0728x over previous
//
#include <hip/hip_runtime.h>
#include <hip/hip_fp16.h>
#include <math.h>

#define N_LEVELS 16
#define LOG2_T 19
#define TABLE_SIZE (1 << LOG2_T)
#define IDX_MASK ((unsigned)(TABLE_SIZE - 1))
#define N_STAGED 4
#define N_FINE (N_LEVELS - N_STAGED)
#define DENSE_CAP 11936            // 4B fp16-pair entries; 47.7 KB LDS
#define THREADS 256
#define PTS_PER_THREAD 4
#define PTS_PER_BLOCK (THREADS * PTS_PER_THREAD)

typedef float f2_t __attribute__((ext_vector_type(2)));
typedef float f4_t __attribute__((ext_vector_type(4)));

struct Params {
    float res[N_LEVELS];
    int   c0[N_STAGED];        // min bottom-left index per staged level (fp32-exact)
    int   K[N_STAGED];         // dense corners per axis
    int   K2[N_STAGED];
    int   base[N_STAGED + 1];  // prefix offsets into dense region
    int   n_pts;
};

// ---- pass 1a: fp16-compress the 12 FINE tables (levels 4..15) into workspace.
// Values in [-1e-4,1e-4]; fp16 abs err ~3e-8 (absmax unchanged rounds 1-3).
__global__ __launch_bounds__(256) void convert_fine(
    const f2_t* __restrict__ emb, unsigned* __restrict__ tab, int n)
{
    int i = blockIdx.x * 256 + threadIdx.x;
    if (i >= n) return;
    f2_t e = __builtin_nontemporal_load(&emb[(size_t)N_STAGED * TABLE_SIZE + i]);
    union { __half2 h2; unsigned u; } c;
    c.h2 = __floats2half2_rn(e.x, e.y);
    __builtin_nontemporal_store(c.u, &tab[i]);
}

// ---- pass 1b: build DENSE re-indexed coarse tables (levels 0..3) over the
// fp32-exact reachable corner box [c0, c0+K). 11,935 hash-gathers, once.
__global__ __launch_bounds__(256) void build_dense(
    const f2_t* __restrict__ emb, unsigned* __restrict__ dense, Params P)
{
    int t = blockIdx.x * 256 + threadIdx.x;
    if (t >= P.base[N_STAGED]) return;
    int lev = 0;
    if (t >= P.base[1]) lev = 1;
    if (t >= P.base[2]) lev = 2;
    if (t >= P.base[3]) lev = 3;
    int li = t - P.base[lev];
    int K  = P.K[lev];
    int kx = li % K; int r2 = li / K; int ky = r2 % K; int kz = r2 / K;
    unsigned cx = (unsigned)(P.c0[lev] + kx);
    unsigned cy = (unsigned)(P.c0[lev] + ky);
    unsigned cz = (unsigned)(P.c0[lev] + kz);
    unsigned h = (cx ^ (cy * 2654435761u) ^ (cz * 805459861u)) & IDX_MASK;
    f2_t e = emb[(size_t)lev * TABLE_SIZE + h];
    union { __half2 h2; unsigned u; } c;
    c.h2 = __floats2half2_rn(e.x, e.y);
    dense[t] = c.u;
}

__device__ __forceinline__ void acc_corner(
    unsigned w0, unsigned w1, float g0, float g1, float& a0, float& a1)
{
    union { unsigned u; __half2 h; } p0, p1;
    p0.u = w0; p1.u = w1;
    a0 += g0 * __low2float(p0.h)  + g1 * __low2float(p1.h);
    a1 += g0 * __high2float(p0.h) + g1 * __high2float(p1.h);
}

// One level's trilinear interpolation for one point. lev is a compile-time
// constant at every call site (unrolled loops) -> the staged/fine branch folds.
__device__ __forceinline__ void level_eval(
    int lev, const Params& P, const unsigned* s_dense,
    const unsigned* __restrict__ tabF, const f2_t* __restrict__ emb,
    float xx, float xy, float xz, float& acc0, float& acc1)
{
    float r = P.res[lev];
    float grid = 2.0f / r;                 // fp32 IEEE div == numpy
    // exact fp32 op sequence of the verified baseline (add, div, floor)
    float tx = (xx + 1.0f) / grid;
    float ty = (xy + 1.0f) / grid;
    float tz = (xz + 1.0f) / grid;
    int blx = (int)floorf(tx);
    int bly = (int)floorf(ty);
    int blz = (int)floorf(tz);
    float wx = (xx - ((float)blx * grid + -1.0f)) / grid;
    float wy = (xy - ((float)bly * grid + -1.0f)) / grid;
    float wz = (xz - ((float)blz * grid + -1.0f)) / grid;

    float fy[2] = {1.0f - wy, wy};
    float fz[2] = {1.0f - wz, wz};
    float fx0 = 1.0f - wx, fx1 = wx;

    acc0 = 0.0f; acc1 = 0.0f;

    if (lev < N_STAGED) {
        // ---- LDS dense path: zero VMEM gathers
        int K = P.K[lev], K2 = P.K2[lev], c0 = P.c0[lev];
        int kx = blx - c0, ky = bly - c0, kz = blz - c0;
        unsigned lim = (unsigned)(K - 1);    // need kx and kx+1 in [0, K)
        if ((unsigned)kx < lim && (unsigned)ky < lim && (unsigned)kz < lim) {
            int i00 = P.base[lev] + (kz * K + ky) * K + kx;
#pragma unroll
            for (int yz = 0; yz < 4; ++yz) {
                int id = i00 + (yz >> 1) * K + (yz & 1) * K2;
                float wyz = fy[yz >> 1] * fz[yz & 1];
                acc_corner(s_dense[id], s_dense[id + 1], fx0 * wyz, fx1 * wyz,
                           acc0, acc1);
            }
        } else {
            // cold safety fallback (corner outside precomputed box): exact f32
            const f2_t* tab = emb + (size_t)lev * TABLE_SIZE;
#pragma unroll
            for (int k = 0; k < 8; ++k) {
                int bx = (k >> 2) & 1, by = (k >> 1) & 1, bz = k & 1;
                unsigned cx = (unsigned)(blx + bx);
                unsigned cy = (unsigned)(bly + by);
                unsigned cz = (unsigned)(blz + bz);
                unsigned h = (cx ^ (cy * 2654435761u) ^ (cz * 805459861u)) & IDX_MASK;
                f2_t e = tab[h];
                float w = (bx ? wx : 1.0f - wx) * fy[by] * fz[bz];
                acc0 += w * e.x;
                acc1 += w * e.y;
            }
        }
    } else {
        // ---- fine path: mod-4 16B group gathers on fp16 tables.
        // i0 = cx^hyz, i1 = (cx+1)^hyz share the aligned 4-group unless cx%4==3.
        const unsigned* tab = tabF + (size_t)(lev - N_STAGED) * TABLE_SIZE;
        unsigned ux  = (unsigned)blx;
        unsigned hy0 = (unsigned)bly * 2654435761u;
        unsigned hy1 = ((unsigned)bly + 1u) * 2654435761u;
        unsigned hz0 = (unsigned)blz * 805459861u;
        unsigned hz1 = ((unsigned)blz + 1u) * 805459861u;
        unsigned w0a[4], w1a[4], i1a[4];
#pragma unroll
        for (int yz = 0; yz < 4; ++yz) {
            unsigned hyz = ((yz & 2) ? hy1 : hy0) ^ ((yz & 1) ? hz1 : hz0);
            unsigned i0 = (ux ^ hyz) & IDX_MASK;
            unsigned i1 = ((ux + 1u) ^ hyz) & IDX_MASK;
            i1a[yz] = i1;
            uint4 g = *(const uint4*)(tab + (i0 & ~3u));   // 16B aligned
            unsigned s0 = i0 & 3u, s1 = i1 & 3u;
            unsigned t0 = (s0 & 1u) ? g.y : g.x;
            unsigned t1 = (s0 & 1u) ? g.w : g.z;
            w0a[yz] = (s0 & 2u) ? t1 : t0;
            unsigned u0 = (s1 & 1u) ? g.y : g.x;
            unsigned u1 = (s1 & 1u) ? g.w : g.z;
            w1a[yz] = (s1 & 2u) ? u1 : u0;   // bogus iff cx%4==3; patched below
        }
        if ((ux & 3u) == 3u) {               // ~25% of lanes
#pragma unroll
            for (int yz = 0; yz < 4; ++yz) w1a[yz] = tab[i1a[yz]];
        }
#pragma unroll
        for (int yz = 0; yz < 4; ++yz) {
            float wyz = fy[yz >> 1] * fz[yz & 1];
            acc_corner(w0a[yz], w1a[yz], fx0 * wyz, fx1 * wyz, acc0, acc1);
        }
    }
}

// ---- pass 2: one thread = one point x ALL 16 levels, 4 points per thread.
__global__ __launch_bounds__(256) void ingp_hash_fused(
    const float* __restrict__ x,
    const unsigned* __restrict__ tabF,
    const unsigned* __restrict__ denseG,
    const f2_t* __restrict__ emb,
    float* __restrict__ out,
    Params P)
{
    __shared__ __align__(16) unsigned s_dense[DENSE_CAP];
    {
        const uint4* src = (const uint4*)denseG;
        uint4* dst = (uint4*)s_dense;
#pragma unroll
        for (int i = 0; i < DENSE_CAP / 4 / THREADS + 1; ++i) {
            int id = i * THREADS + (int)threadIdx.x;
            if (id < DENSE_CAP / 4) dst[id] = src[id];
        }
    }
    __syncthreads();

    int base_pt = blockIdx.x * PTS_PER_BLOCK;
#pragma unroll 1
    for (int j = 0; j < PTS_PER_THREAD; ++j) {
        int n = base_pt + j * THREADS + (int)threadIdx.x;
        if (n >= P.n_pts) break;             // no syncs below: safe divergence

        float xx = fminf(fmaxf(__builtin_nontemporal_load(&x[n * 3 + 0]), -1.0f), 1.0f);
        float xy = fminf(fmaxf(__builtin_nontemporal_load(&x[n * 3 + 1]), -1.0f), 1.0f);
        float xz = fminf(fmaxf(__builtin_nontemporal_load(&x[n * 3 + 2]), -1.0f), 1.0f);

        float* orow = out + (size_t)n * (N_LEVELS * 2);
#pragma unroll
        for (int lp = 0; lp < N_LEVELS / 2; ++lp) {
            float a0, a1, b0, b1;
            level_eval(2 * lp + 0, P, s_dense, tabF, emb, xx, xy, xz, a0, a1);
            level_eval(2 * lp + 1, P, s_dense, tabF, emb, xx, xy, xz, b0, b1);
            f4_t o4 = {a0, a1, b0, b1};
            __builtin_nontemporal_store(o4, (f4_t*)(orow + lp * 4));
        }
    }
}

// ---- fallback (ws unavailable): round-3 proven f32 pair kernel.
__global__ __launch_bounds__(256) void ingp_hash_pair_f32(
    const float* __restrict__ x, const f2_t* __restrict__ emb,
    float* __restrict__ out, Params P)
{
    int b = blockIdx.x;
    int slot = b & 7;
    int n = (b >> 3) * 256 + (int)threadIdx.x;
    if (n >= P.n_pts) return;
    float xx = fminf(fmaxf(x[n * 3 + 0], -1.0f), 1.0f);
    float xy = fminf(fmaxf(x[n * 3 + 1], -1.0f), 1.0f);
    float xz = fminf(fmaxf(x[n * 3 + 2], -1.0f), 1.0f);
    f4_t o4;
#pragma unroll
    for (int hl = 0; hl < 2; ++hl) {
        int lev = 2 * slot + hl;
        float grid = 2.0f / P.res[lev];
        int blx = (int)floorf((xx + 1.0f) / grid);
        int bly = (int)floorf((xy + 1.0f) / grid);
        int blz = (int)floorf((xz + 1.0f) / grid);
        float wx = (xx - ((float)blx * grid + -1.0f)) / grid;
        float wy = (xy - ((float)bly * grid + -1.0f)) / grid;
        float wz = (xz - ((float)blz * grid + -1.0f)) / grid;
        const f2_t* tab = emb + (size_t)lev * TABLE_SIZE;
        float acc0 = 0.0f, acc1 = 0.0f;
#pragma unroll
        for (int k = 0; k < 8; ++k) {
            int bx = (k >> 2) & 1, by = (k >> 1) & 1, bz = k & 1;
            unsigned h = ((unsigned)(blx + bx)
                          ^ ((unsigned)(bly + by) * 2654435761u)
                          ^ ((unsigned)(blz + bz) * 805459861u)) & IDX_MASK;
            f2_t e = tab[h];
            float w = (bx ? wx : 1.0f - wx) * (by ? wy : 1.0f - wy) * (bz ? wz : 1.0f - wz);
            acc0 += w * e.x; acc1 += w * e.y;
        }
        if (hl == 0) { o4.x = acc0; o4.y = acc1; } else { o4.z = acc0; o4.w = acc1; }
    }
    __builtin_nontemporal_store(o4, (f4_t*)(out + (size_t)n * (N_LEVELS * 2) + slot * 4));
}

extern "C" void kernel_launch(void* const* d_in, const int* in_sizes, int n_in,
                              void* d_out, int out_size, void* d_ws, size_t ws_size,
                              hipStream_t stream) {
    const float* x   = (const float*)d_in[0];
    const float* emb = (const float*)d_in[1];
    float* out = (float*)d_out;
    int n_pts = in_sizes[0] / 3;

    Params P;
    // RESOLUTIONS: numpy float64 semantics on host (same libm as np)
    double b = exp((log(512.0) - log(16.0)) / 15.0);
    for (int i = 0; i < N_LEVELS; ++i)
        P.res[i] = (float)floor(16.0 * pow(b, (double)i));
    P.n_pts = n_pts;

    // Dense box bounds per staged level, computed with the SAME fp32 ops the
    // device uses: bl(x) = floorf((x+1)/grid) is monotone in x, x in [0,1) ->
    // blmin = bl(0), blmax = bl(max) with (x+1) <= 2.0f after fp32 rounding.
    int base = 0;
    for (int l = 0; l < N_STAGED; ++l) {
        float grid = 2.0f / P.res[l];
        int blmin = (int)floorf(1.0f / grid);
        int blmax = (int)floorf(2.0f / grid);
        int K = blmax - blmin + 2;     // corners blmin .. blmax+1
        P.c0[l] = blmin; P.K[l] = K; P.K2[l] = K * K;
        P.base[l] = base; base += K * K * K;
    }
    P.base[N_STAGED] = base;

    size_t need = (size_t)N_FINE * TABLE_SIZE * 4 + (size_t)DENSE_CAP * 4;
    if (base <= DENSE_CAP && ws_size >= need && d_ws != nullptr) {
        unsigned* tabF   = (unsigned*)d_ws;
        unsigned* denseG = tabF + (size_t)N_FINE * TABLE_SIZE;
        int nF = N_FINE * TABLE_SIZE;
        hipLaunchKernelGGL(convert_fine, dim3((nF + 255) / 256), dim3(256), 0, stream,
                           (const f2_t*)emb, tabF, nF);
        hipLaunchKernelGGL(build_dense, dim3((base + 255) / 256), dim3(256), 0, stream,
                           (const f2_t*)emb, denseG, P);
        int blocks = (n_pts + PTS_PER_BLOCK - 1) / PTS_PER_BLOCK;
        hipLaunchKernelGGL(ingp_hash_fused, dim3(blocks), dim3(256), 0, stream,
                           x, tabF, denseG, (const f2_t*)emb, out, P);
    } else {
        int blocks = 8 * ((n_pts + 255) / 256);
        hipLaunchKernelGGL(ingp_hash_pair_f32, dim3(blocks), dim3(256), 0, stream,
                           x, (const f2_t*)emb, out, P);
    }
}